// Round 1
// 3902.474 us; speedup vs baseline: 1.4013x; 1.4013x over previous
//
#include <hip/hip_runtime.h>
#include <math.h>

#define DEV static __device__ __forceinline__

typedef __bf16 bf16x8 __attribute__((ext_vector_type(8)));
typedef float f32x4 __attribute__((ext_vector_type(4)));
typedef unsigned short ushort8v __attribute__((ext_vector_type(8)));

constexpr int B_ = 4, T_ = 1024, V_ = 32000, D_ = 1024, H_ = 16, HD_ = 64;

// ---------- helpers ----------
DEV unsigned short f2bf(float x){            // fp32 -> bf16 bits, RNE
  unsigned u = __builtin_bit_cast(unsigned, x);
  u += 0x7FFFu + ((u >> 16) & 1u);
  return (unsigned short)(u >> 16);
}
DEV f32x4 mfma_bf16(bf16x8 a, bf16x8 b, f32x4 c){
  return __builtin_amdgcn_mfma_f32_16x16x32_bf16(a, b, c, 0, 0, 0);
}
DEV bf16x8 as_bf(int4 v){ return __builtin_bit_cast(bf16x8, v); }

// LDS granule swizzles (16B granules).
DEV int swz4 (int row, int kq){ return row*4  + (kq ^ ((row >> 1) & 3)); }
DEV int swz8 (int row, int kq){ return row*8  + (kq ^ (row & 7)); }
DEV int swz16(int row, int kq){ return row*16 + (kq ^ (row & 15)); }

// async global->LDS, 16B per lane, dest = base + lane*16 (linear)
#pragma clang diagnostic push
#pragma clang diagnostic ignored "-Waddress-space-conversion"
DEV void gload16(const void* g, void* l){
  __builtin_amdgcn_global_load_lds(
      (const __attribute__((address_space(1))) void*)g,
      (__attribute__((address_space(3))) void*)l, 16, 0, 0);
}
#pragma clang diagnostic pop

// ---------- embedding: x = tok_emb[idx] + pos_emb ----------
__global__ void k_embed(const int* __restrict__ idx, const float* __restrict__ tok,
                        const float* __restrict__ pos, float* __restrict__ x){
  const int row = blockIdx.x;           // 0..4095  (b*T+t)
  const int t = row & (T_ - 1);
  const int col = threadIdx.x * 4;
  const int id = idx[row];
  const float4 a = *(const float4*)(tok + (size_t)id * D_ + col);
  const float4 p = *(const float4*)(pos + (size_t)t  * D_ + col);
  float4 r; r.x = a.x + p.x; r.y = a.y + p.y; r.z = a.z + p.z; r.w = a.w + p.w;
  *(float4*)(x + (size_t)row * D_ + col) = r;
}

// ---------- LayerNorm (fp32 in, bf16 out), one block per row ----------
__global__ void k_ln(const float* __restrict__ x, const float* __restrict__ g,
                     const float* __restrict__ b, unsigned short* __restrict__ h){
  __shared__ float red[8];
  const int row = blockIdx.x, tid = threadIdx.x;
  const int lane = tid & 63, wv = tid >> 6;
  const float4 v = *(const float4*)(x + (size_t)row * D_ + tid * 4);
  float s = v.x + v.y + v.z + v.w;
  #pragma unroll
  for (int m = 32; m >= 1; m >>= 1) s += __shfl_xor(s, m, 64);
  if (lane == 0) red[wv] = s;
  __syncthreads();
  const float mean = (red[0] + red[1] + red[2] + red[3]) * (1.0f / D_);
  const float dx = v.x - mean, dy = v.y - mean, dz = v.z - mean, dw = v.w - mean;
  float q2 = dx*dx + dy*dy + dz*dz + dw*dw;
  #pragma unroll
  for (int m = 32; m >= 1; m >>= 1) q2 += __shfl_xor(q2, m, 64);
  if (lane == 0) red[4 + wv] = q2;
  __syncthreads();
  const float var = (red[4] + red[5] + red[6] + red[7]) * (1.0f / D_);
  const float rs = rsqrtf(var + 1e-5f);
  const float4 gg = *(const float4*)(g + tid * 4);
  const float4 bb = *(const float4*)(b + tid * 4);
  ushort4 o;
  o.x = f2bf(dx * rs * gg.x + bb.x);
  o.y = f2bf(dy * rs * gg.y + bb.y);
  o.z = f2bf(dz * rs * gg.z + bb.z);
  o.w = f2bf(dw * rs * gg.w + bb.w);
  *(ushort4*)(h + (size_t)row * D_ + tid * 4) = o;
}

// ---------- weight transpose+convert: out_bf16[n][k] = in_f32[k][n] ----------
DEV void cvt_tile(const float* __restrict__ in, unsigned short* __restrict__ out,
                  int K, int N, int k0, int n0){
  __shared__ float tile[64][65];
  const int tid = threadIdx.x;
  const int r = tid >> 4, c4 = (tid & 15) * 4;
  #pragma unroll
  for (int p = 0; p < 4; p++){
    const float4 v = *(const float4*)(in + (size_t)(k0 + r + p*16) * N + n0 + c4);
    tile[r + p*16][c4+0] = v.x;
    tile[r + p*16][c4+1] = v.y;
    tile[r + p*16][c4+2] = v.z;
    tile[r + p*16][c4+3] = v.w;
  }
  __syncthreads();
  const int wr = tid >> 3, wc = tid & 7;
  #pragma unroll
  for (int p = 0; p < 2; p++){
    const int n = wr + p*32;
    ushort8v o;
    #pragma unroll
    for (int jj = 0; jj < 8; jj++) o[jj] = f2bf(tile[wc*8 + jj][n]);
    *(ushort8v*)(out + (size_t)(n0 + n) * K + k0 + wc*8) = o;
  }
}

__global__ void k_cvtT(const float* __restrict__ in, unsigned short* __restrict__ out,
                       int K, int N){
  cvt_tile(in, out, K, N, blockIdx.x * 64, blockIdx.y * 64);
}

// 4x [1024][1024] (q,k,v,o) into contiguous dst slices
__global__ void k_cvtT4(const float* __restrict__ s0, const float* __restrict__ s1,
                        const float* __restrict__ s2, const float* __restrict__ s3,
                        unsigned short* __restrict__ dst){
  const int z = blockIdx.z;
  const float* in = (z == 0) ? s0 : (z == 1) ? s1 : (z == 2) ? s2 : s3;
  cvt_tile(in, dst + (size_t)z * 1048576, 1024, 1024, blockIdx.x * 64, blockIdx.y * 64);
}

// ---------- GEMM: C[M,N] = A_bf16[M,K] @ Bt_bf16[N,K]^T (+bias)(+epilogue) ----------
enum { MODE_GELU = 1, MODE_RESID = 2, MODE_HEAD = 3, MODE_QKV = 5 };

template<int MODE>
__global__ __launch_bounds__(256)
void k_gemm(const unsigned short* __restrict__ A, const unsigned short* __restrict__ Bt,
            const float* __restrict__ bias, const float* __restrict__ bias2,
            const float* __restrict__ bias3, void* __restrict__ outp, int N, int K){
  __shared__ int4 As[1024];   // 2 halves x [128 rows][4 granules], swz4 content
  __shared__ int4 Bs[1024];
  const int m0 = blockIdx.x * 128, n0 = blockIdx.y * 128;
  const int tid = threadIdx.x, lane = tid & 63, wv = tid >> 6;
  const int wm = wv >> 1, wn = wv & 1;
  const int l15 = lane & 15, l4 = lane >> 4;

  f32x4 acc[4][4];
  const f32x4 zero = {0.f, 0.f, 0.f, 0.f};
  #pragma unroll
  for (int i = 0; i < 4; i++)
    #pragma unroll
    for (int j = 0; j < 4; j++) acc[i][j] = zero;

  // staging geometry: wave wv owns LDS granules [wv*128, wv*128+128) of each half.
  // lane l, instr i: linear granule = wv*128 + i*64 + l -> row = g>>2, kq' = g&3.
  // LDS is written linearly; the SOURCE k-chunk is pre-swizzled so that
  // granule (row,kq') holds chunk kq'^s(row), i.e. exactly swz4 content.
  const int g0 = wv * 128 + lane;
  const int row0 = g0 >> 2, kc0 = (g0 & 3) ^ ((row0 >> 1) & 3);
  const int g1 = g0 + 64;
  const int row1 = g1 >> 2, kc1 = (g1 & 3) ^ ((row1 >> 1) & 3);
  const unsigned short* Ap0 = A  + (size_t)(m0 + row0) * K + kc0 * 8;
  const unsigned short* Ap1 = A  + (size_t)(m0 + row1) * K + kc1 * 8;
  const unsigned short* Bp0 = Bt + (size_t)(n0 + row0) * K + kc0 * 8;
  const unsigned short* Bp1 = Bt + (size_t)(n0 + row1) * K + kc1 * 8;

  // prologue: stage tile 0 into half 0
  gload16(Ap0, As + wv*128);       gload16(Ap1, As + wv*128 + 64);
  gload16(Bp0, Bs + wv*128);       gload16(Bp1, Bs + wv*128 + 64);

  int cur = 0;
  for (int kt = 0; kt < K; kt += 32){
    __syncthreads();                        // implicit vmcnt(0): tile kt ready
    if (kt + 32 < K){                       // stage next tile into other half
      Ap0 += 32; Ap1 += 32; Bp0 += 32; Bp1 += 32;
      const int nx = cur ^ 1;
      gload16(Ap0, As + nx*512 + wv*128);
      gload16(Ap1, As + nx*512 + wv*128 + 64);
      gload16(Bp0, Bs + nx*512 + wv*128);
      gload16(Bp1, Bs + nx*512 + wv*128 + 64);
    }
    const int4* const Ac = As + cur*512;
    const int4* const Bc = Bs + cur*512;
    bf16x8 af[4], bfr[4];
    #pragma unroll
    for (int i = 0; i < 4; i++) af[i]  = as_bf(Ac[swz4(wm*64 + i*16 + l15, l4)]);
    #pragma unroll
    for (int j = 0; j < 4; j++) bfr[j] = as_bf(Bc[swz4(wn*64 + j*16 + l15, l4)]);
    #pragma unroll
    for (int i = 0; i < 4; i++)
      #pragma unroll
      for (int j = 0; j < 4; j++)
        acc[i][j] = mfma_bf16(af[i], bfr[j], acc[i][j]);
    cur ^= 1;
  }

  // epilogue. C/D layout: row = quad*4 + r, col = lane&15
  #pragma unroll
  for (int i = 0; i < 4; i++){
    const int mr = m0 + wm*64 + i*16 + l4*4;
    #pragma unroll
    for (int j = 0; j < 4; j++){
      const int nc = n0 + wn*64 + j*16 + l15;
      if constexpr (MODE == MODE_QKV){
        // N=3072 fused q|k|v. seg uniform per block (128 | 1024 boundaries).
        const int seg = nc >> 10, c = nc & 1023;
        const float* bp = (seg == 0) ? bias : (seg == 1) ? bias2 : bias3;
        const float bb = bp[c];
        unsigned short* const o16 = (unsigned short*)outp;   // qbf base; kbf=+4M, vtb=+8M
        if (seg == 2){
          // v transposed: vt[((b*H + h)*HD + hd)*T + t], 4 consecutive t
          const int t = mr & (T_ - 1), bbat = mr >> 10;
          const int hh = c >> 6, hd = c & 63;
          ushort4 w;
          w.x = f2bf(acc[i][j][0] + bb);
          w.y = f2bf(acc[i][j][1] + bb);
          w.z = f2bf(acc[i][j][2] + bb);
          w.w = f2bf(acc[i][j][3] + bb);
          *(ushort4*)(o16 + (size_t)8*1048576 +
                      ((size_t)((bbat*H_ + hh)*HD_ + hd)) * T_ + t) = w;
        } else {
          unsigned short* dst = o16 + (size_t)seg * 4194304;
          #pragma unroll
          for (int r = 0; r < 4; r++)
            dst[(size_t)(mr + r) * D_ + c] = f2bf(acc[i][j][r] + bb);
        }
      } else {
        const float bb = (MODE == MODE_HEAD) ? 0.f : bias[nc];
        #pragma unroll
        for (int r = 0; r < 4; r++){
          const float v = acc[i][j][r] + bb;
          const size_t oi = (size_t)(mr + r) * N + nc;
          if constexpr (MODE == MODE_GELU)
            ((unsigned short*)outp)[oi] = f2bf(0.5f * v * (1.f + erff(v * 0.70710678118654752f)));
          else if constexpr (MODE == MODE_RESID)
            ((float*)outp)[oi] += v;
          else
            ((float*)outp)[oi] = v;
        }
      }
    }
  }
}

// ---------- flash attention: 128-q block, 128-key tiles, online softmax ----------
__global__ __launch_bounds__(256)
void k_attn(const unsigned short* __restrict__ q, const unsigned short* __restrict__ k,
            const unsigned short* __restrict__ vt, unsigned short* __restrict__ o){
  __shared__ int4 SH[4096];               // 64 KiB exactly
  int4* const Qs = SH;                    // [0,1024)    Q  [128 q][64 hd]
  int4* const Vs = SH + 1024;             // [1024,2048) V^T[64 hd][128 key]
  int4* const Ks = SH + 2048;             // [2048,3072) K  [128 key][64 hd]
  int4* const Ps = SH + 2048;             // [2048,4096) P  [128 q][128 key] overlays Ks

  const int qb = blockIdx.x;              // q tile 0..7
  const int bh = blockIdx.y, bb = bh >> 4, hh = bh & 15;
  const int q0 = qb * 128;
  const int tid = threadIdx.x, lane = tid & 63, wv = tid >> 6;
  const int l15 = lane & 15, l4 = lane >> 4;

  const unsigned short* qp = q  + (size_t)(bb*T_ + q0) * D_ + hh*HD_;
  const unsigned short* kp = k  + (size_t)bb * T_ * D_ + hh*HD_;
  const unsigned short* vp = vt + (size_t)(bh*HD_) * T_;

  { // stage Q once
    const int row = tid >> 1, half = tid & 1;
    const int4* src = (const int4*)(qp + (size_t)row * D_ + half*32);
    #pragma unroll
    for (int j = 0; j < 4; j++) Qs[swz8(row, half*4 + j)] = src[j];
  }

  const f32x4 zero = {0.f, 0.f, 0.f, 0.f};
  f32x4 O[2][4];
  #pragma unroll
  for (int i = 0; i < 2; i++)
    #pragma unroll
    for (int j = 0; j < 4; j++) O[i][j] = zero;
  float mrow[8], lrow[8];
  #pragma unroll
  for (int i = 0; i < 8; i++){ mrow[i] = -1e30f; lrow[i] = 0.f; }

  for (int kt = 0; kt <= qb; kt++){
    const int k0 = kt * 128;
    __syncthreads();                       // prev iter LDS reads done
    {
      const int row = tid >> 1, half = tid & 1;
      const int4* src = (const int4*)(kp + (size_t)(k0 + row) * D_ + half*32);
      #pragma unroll
      for (int j = 0; j < 4; j++) Ks[swz8(row, half*4 + j)] = src[j];
      const int hd = tid >> 2, qu = tid & 3;
      const int4* sv = (const int4*)(vp + (size_t)hd * T_ + k0 + qu*32);
      #pragma unroll
      for (int j = 0; j < 4; j++) Vs[swz16(hd, qu*4 + j)] = sv[j];
    }
    __syncthreads();

    // S = Q K^T  (wave handles 32 q rows x 128 keys)
    f32x4 s[2][8];
    #pragma unroll
    for (int i = 0; i < 2; i++)
      #pragma unroll
      for (int j = 0; j < 8; j++) s[i][j] = zero;
    #pragma unroll
    for (int ks = 0; ks < 2; ks++){
      bf16x8 aq[2];
      #pragma unroll
      for (int i = 0; i < 2; i++) aq[i] = as_bf(Qs[swz8(wv*32 + i*16 + l15, ks*4 + l4)]);
      #pragma unroll
      for (int j = 0; j < 8; j++){
        const bf16x8 bk = as_bf(Ks[swz8(j*16 + l15, ks*4 + l4)]);
        s[0][j] = mfma_bf16(aq[0], bk, s[0][j]);
        s[1][j] = mfma_bf16(aq[1], bk, s[1][j]);
      }
    }

    // online softmax (per q row; row = wv*32 + i*16 + quad*4 + r)
    const bool diag = (kt == qb);
    #pragma unroll
    for (int i = 0; i < 2; i++){
      #pragma unroll
      for (int r = 0; r < 4; r++){
        const int ridx = i*4 + r;
        const int qrow = q0 + wv*32 + i*16 + l4*4 + r;
        float mx = -1e30f;
        #pragma unroll
        for (int j = 0; j < 8; j++){
          float val = s[i][j][r] * 0.125f;
          if (diag && (k0 + j*16 + l15) > qrow) val = -1e30f;
          s[i][j][r] = val;
          mx = fmaxf(mx, val);
        }
        #pragma unroll
        for (int mk = 1; mk < 16; mk <<= 1) mx = fmaxf(mx, __shfl_xor(mx, mk, 64));
        const float mnew = fmaxf(mrow[ridx], mx);
        const float alpha = __expf(mrow[ridx] - mnew);
        mrow[ridx] = mnew;
        float rs = 0.f;
        #pragma unroll
        for (int j = 0; j < 8; j++){
          const float p = __expf(s[i][j][r] - mnew);
          s[i][j][r] = p;
          rs += p;
        }
        #pragma unroll
        for (int mk = 1; mk < 16; mk <<= 1) rs += __shfl_xor(rs, mk, 64);
        lrow[ridx] = lrow[ridx] * alpha + rs;
        #pragma unroll
        for (int j = 0; j < 4; j++) O[i][j][r] *= alpha;
      }
    }

    __syncthreads();                       // all Ks reads done before Ps overlay write
    // P (C-layout regs) -> LDS bf16 (A-layout readable)
    #pragma unroll
    for (int i = 0; i < 2; i++)
      #pragma unroll
      for (int j = 0; j < 8; j++){
        const int pc = j*16 + l15;
        #pragma unroll
        for (int r = 0; r < 4; r++){
          const int pr = wv*32 + i*16 + l4*4 + r;
          ((unsigned short*)&Ps[swz16(pr, pc >> 3)])[pc & 7] = f2bf(s[i][j][r]);
        }
      }

    // O += P @ V  (wave reads only its own Ps rows -> no barrier needed)
    #pragma unroll
    for (int ks = 0; ks < 4; ks++){
      bf16x8 ap[2];
      #pragma unroll
      for (int i = 0; i < 2; i++) ap[i] = as_bf(Ps[swz16(wv*32 + i*16 + l15, ks*4 + l4)]);
      #pragma unroll
      for (int j = 0; j < 4; j++){
        const bf16x8 bv = as_bf(Vs[swz16(j*16 + l15, ks*4 + l4)]);
        O[0][j] = mfma_bf16(ap[0], bv, O[0][j]);
        O[1][j] = mfma_bf16(ap[1], bv, O[1][j]);
      }
    }
  }

  unsigned short* op = o + (size_t)(bb*T_ + q0) * D_ + hh*HD_;
  #pragma unroll
  for (int i = 0; i < 2; i++)
    #pragma unroll
    for (int r = 0; r < 4; r++){
      const float inv = 1.f / lrow[i*4 + r];
      const int tr = wv*32 + i*16 + l4*4 + r;
      #pragma unroll
      for (int j = 0; j < 4; j++)
        op[(size_t)tr * D_ + j*16 + l15] = f2bf(O[i][j][r] * inv);
    }
}

// ---------- launch ----------
extern "C" void kernel_launch(void* const* d_in, const int* in_sizes, int n_in,
                              void* d_out, int out_size, void* d_ws, size_t ws_size,
                              hipStream_t stream){
  (void)in_sizes; (void)n_in; (void)out_size; (void)ws_size;
  const int*   idx     = (const int*)d_in[0];
  const float* tok_emb = (const float*)d_in[1];
  const float* pos_emb = (const float*)d_in[2];
  const float* ln1_g = (const float*)d_in[3];
  const float* ln1_b = (const float*)d_in[4];
  const float* Wq = (const float*)d_in[5];
  const float* bq = (const float*)d_in[6];
  const float* Wk = (const float*)d_in[7];
  const float* bk = (const float*)d_in[8];
  const float* Wv = (const float*)d_in[9];
  const float* bv = (const float*)d_in[10];
  const float* Wo = (const float*)d_in[11];
  const float* bo = (const float*)d_in[12];
  const float* ln2_g = (const float*)d_in[13];
  const float* ln2_b = (const float*)d_in[14];
  const float* W1 = (const float*)d_in[15];
  const float* b1 = (const float*)d_in[16];
  const float* W2 = (const float*)d_in[17];
  const float* b2 = (const float*)d_in[18];
  const float* lnf_g = (const float*)d_in[19];
  const float* lnf_b = (const float*)d_in[20];
  const float* head_W = (const float*)d_in[21];

  char* w = (char*)d_ws;
  float* x            = (float*)w;          w += (size_t)4096*1024*4;
  unsigned short* h   = (unsigned short*)w; w += (size_t)4096*1024*2;
  unsigned short* qbf = (unsigned short*)w; w += (size_t)4096*1024*2;  // qbf|kbf|vtb contiguous
  unsigned short* kbf = (unsigned short*)w; w += (size_t)4096*1024*2;
  unsigned short* vtb = (unsigned short*)w; w += (size_t)4096*1024*2;
  unsigned short* ob  = (unsigned short*)w; w += (size_t)4096*1024*2;
  unsigned short* act = (unsigned short*)w; w += (size_t)4096*4096*2;
  unsigned short* wqkvo = (unsigned short*)w; w += (size_t)4*1024*1024*2;  // [q|k|v|o][1024][1024] bf16 T
  unsigned short* wt1 = (unsigned short*)w; w += (size_t)4096*1024*2;      // W1^T [4096][1024]
  unsigned short* wt2 = (unsigned short*)w; w += (size_t)4096*1024*2;      // W2^T [1024][4096]
  unsigned short* wth = (unsigned short*)w; w += (size_t)32000*1024*2;     // head^T [32000][1024]

  const dim3 blk(256);
  const dim3 gRow(4096);
  const dim3 gD(32, 8), gQKV(32, 24), gFF(32, 32), gHead(32, 250), gAtt(8, 64);

  k_embed<<<gRow, blk, 0, stream>>>(idx, tok_emb, pos_emb, x);
  for (int l = 0; l < 8; l++){
    const size_t w2 = (size_t)l*1024*1024, b1o = (size_t)l*1024;
    k_cvtT4<<<dim3(16,16,4), blk, 0, stream>>>(Wq + w2, Wk + w2, Wv + w2, Wo + w2, wqkvo);
    k_cvtT <<<dim3(16,64), blk, 0, stream>>>(W1 + (size_t)l*1024*4096, wt1, 1024, 4096);
    k_cvtT <<<dim3(64,16), blk, 0, stream>>>(W2 + (size_t)l*4096*1024, wt2, 4096, 1024);
    k_ln<<<gRow, blk, 0, stream>>>(x, ln1_g + b1o, ln1_b + b1o, h);
    k_gemm<MODE_QKV><<<gQKV, blk, 0, stream>>>(h, wqkvo, bq + b1o, bk + b1o, bv + b1o,
                                               qbf, 3072, 1024);
    k_attn<<<gAtt, blk, 0, stream>>>(qbf, kbf, vtb, ob);
    k_gemm<MODE_RESID><<<gD, blk, 0, stream>>>(ob, wqkvo + (size_t)3*1048576, bo + b1o,
                                               nullptr, nullptr, x, 1024, 1024);
    k_ln<<<gRow, blk, 0, stream>>>(x, ln2_g + b1o, ln2_b + b1o, h);
    k_gemm<MODE_GELU><<<gFF, blk, 0, stream>>>(h, wt1, b1 + (size_t)l*4096,
                                               nullptr, nullptr, act, 4096, 1024);
    k_gemm<MODE_RESID><<<gD, blk, 0, stream>>>(act, wt2, b2 + b1o,
                                               nullptr, nullptr, x, 1024, 4096);
  }
  k_cvtT<<<dim3(16,500), blk, 0, stream>>>(head_W, wth, 1024, 32000);
  k_ln<<<gRow, blk, 0, stream>>>(x, lnf_g, lnf_b, h);
  k_gemm<MODE_HEAD><<<gHead, blk, 0, stream>>>(h, wth, nullptr, nullptr, nullptr,
                                               (float*)d_out, 32000, 1024);
}